// Round 2
// baseline (320.240 us; speedup 1.0000x reference)
//
#include <hip/hip_runtime.h>

#define RANK    64
#define N_GAMMA 7
#define N_ALPHA 64
#define WLEN    (N_GAMMA * N_ALPHA)   // 448 floats in W

// Kernel 1: W[i][j] = sum_r gamma[r][i] * alpha[r][j]  -> d_ws (448 floats)
__global__ void __launch_bounds__(512) compute_w_kernel(
    const float* __restrict__ gamma,   // [64,7]
    const float* __restrict__ alpha,   // [64,64]
    float* __restrict__ w) {           // [448]
    int t = threadIdx.x;
    if (t < WLEN) {
        int i = t >> 6;       // 0..6
        int j = t & 63;       // 0..63
        float s = 0.f;
#pragma unroll
        for (int r = 0; r < RANK; ++r)
            s = fmaf(gamma[r * N_GAMMA + i], alpha[r * N_ALPHA + j], s);
        w[t] = s;
    }
}

// Kernel 2: one wave handles 4 consecutive rows (448 contiguous float4).
// Lane l, iter i reads float4 #(i*64+l) of the group: coalesced 1KiB/instr.
__global__ void __launch_bounds__(256) cp_dot_kernel(
    const float4* __restrict__ x4,     // [N/4 groups][448 float4]
    const float* __restrict__ beta,    // [1]
    const float* __restrict__ w,       // [448]
    float* __restrict__ y,             // [N]
    int nGroups) {
    const int lane = threadIdx.x & 63;
    const float4* __restrict__ w4 = (const float4*)w;   // 112 float4

    // Per-(lane,i) constants: which of the 4 rows this float4 belongs to,
    // and the matching W fragment. Hoisted out of the grid-stride loop.
    float4 wv[7];
    int rowid[7];
#pragma unroll
    for (int i = 0; i < 7; ++i) {
        int j = i * 64 + lane;        // group-local float4 index, 0..447
        rowid[i] = j / 112;           // row within the 4-row group
        wv[i] = w4[j % 112];          // W fragment for floats 4j..4j+3 of that row
    }
    const float beta0 = beta[0];

    const int wave   = blockIdx.x * (blockDim.x >> 6) + (threadIdx.x >> 6);
    const int nWaves = gridDim.x * (blockDim.x >> 6);

    for (int g = wave; g < nGroups; g += nWaves) {
        const float4* __restrict__ p = x4 + (size_t)g * 448;
        float a0 = 0.f, a1 = 0.f, a2 = 0.f, a3 = 0.f;
#pragma unroll
        for (int i = 0; i < 7; ++i) {
            float4 v = p[i * 64 + lane];
            float dot = fmaf(v.x, wv[i].x,
                        fmaf(v.y, wv[i].y,
                        fmaf(v.z, wv[i].z, v.w * wv[i].w)));
            a0 += (rowid[i] == 0) ? dot : 0.f;
            a1 += (rowid[i] == 1) ? dot : 0.f;
            a2 += (rowid[i] == 2) ? dot : 0.f;
            a3 += (rowid[i] == 3) ? dot : 0.f;
        }
        // Butterfly reduce across the 64-lane wave (all lanes end with totals).
#pragma unroll
        for (int off = 32; off >= 1; off >>= 1) {
            a0 += __shfl_xor(a0, off, 64);
            a1 += __shfl_xor(a1, off, 64);
            a2 += __shfl_xor(a2, off, 64);
            a3 += __shfl_xor(a3, off, 64);
        }
        if (lane < 4) {
            float v = (lane == 0) ? a0 : (lane == 1) ? a1 : (lane == 2) ? a2 : a3;
            y[g * 4 + lane] = beta0 + v;
        }
    }
}

extern "C" void kernel_launch(void* const* d_in, const int* in_sizes, int n_in,
                              void* d_out, int out_size, void* d_ws, size_t ws_size,
                              hipStream_t stream) {
    const float* x     = (const float*)d_in[0];   // [N,7,64]
    const float* beta  = (const float*)d_in[1];   // [1]
    const float* gamma = (const float*)d_in[2];   // [64,7]
    const float* alpha = (const float*)d_in[3];   // [64,64]
    float* y = (float*)d_out;
    float* w = (float*)d_ws;                      // 448 floats of scratch

    const int n = in_sizes[0] / WLEN;             // 131072
    const int nGroups = n / 4;                    // 32768 (N divisible by 4)

    compute_w_kernel<<<1, 512, 0, stream>>>(gamma, alpha, w);

    const int blocks = 2048;                      // 8192 waves, 4 groups each
    cp_dot_kernel<<<blocks, 256, 0, stream>>>((const float4*)x, beta, w, y, nGroups);
}